// Round 1
// baseline (675.701 us; speedup 1.0000x reference)
//
#include <hip/hip_runtime.h>
#include <hip/hip_bf16.h>

#define DIN 512
#define HID 512

// ---------------------------------------------------------------------------
// CSR build: count incoming edges per node
// ---------------------------------------------------------------------------
__global__ void count_kernel(const int* __restrict__ dst, int* __restrict__ cnt, int E) {
    int e = blockIdx.x * 256 + threadIdx.x;
    if (e >= E) return;
    atomicAdd(&cnt[dst[e]], 1);
}

// Single-block exclusive scan over cnt -> offs[N+1], plus dis = rsqrt(deg+1)
__global__ void scan_kernel(const int* __restrict__ cnt, int* __restrict__ offs,
                            float* __restrict__ dis, int N) {
    __shared__ int sm[1024];
    __shared__ int s_carry;
    int tid = threadIdx.x;
    if (tid == 0) s_carry = 0;
    __syncthreads();
    for (int base = 0; base < N; base += 1024) {
        int i = base + tid;
        int v = (i < N) ? cnt[i] : 0;
        sm[tid] = v;
        __syncthreads();
        for (int ofs = 1; ofs < 1024; ofs <<= 1) {
            int t = (tid >= ofs) ? sm[tid - ofs] : 0;
            __syncthreads();
            sm[tid] += t;
            __syncthreads();
        }
        if (i < N) {
            offs[i] = s_carry + sm[tid] - v;          // exclusive
            dis[i]  = rsqrtf((float)v + 1.0f);        // deg includes self-loop
        }
        __syncthreads();
        if (tid == 1023) s_carry += sm[1023];
        __syncthreads();
    }
    if (tid == 0) offs[N] = s_carry;
}

__global__ void fill_kernel(const int* __restrict__ src, const int* __restrict__ dst,
                            const int* __restrict__ offs, int* __restrict__ cursor,
                            int* __restrict__ csr, int E) {
    int e = blockIdx.x * 256 + threadIdx.x;
    if (e >= E) return;
    int d = dst[e];
    int pos = offs[d] + atomicAdd(&cursor[d], 1);
    csr[pos] = src[e];
}

// ---------------------------------------------------------------------------
// fp32 GEMM: C[M,512] = A[M,512] @ B[512,512].  128x128 tile, BK=8,
// 256 threads, 8x8 micro-tile per thread.
// ---------------------------------------------------------------------------
#define BM 128
#define BN 128
#define BK 8

__global__ __launch_bounds__(256) void gemm_f32(const float* __restrict__ A,
                                                const float* __restrict__ B,
                                                float* __restrict__ C, int M) {
    const int K = 512, NN = 512;
    __shared__ float As[BK][BM];   // transposed: As[k][m]
    __shared__ float Bs[BK][BN];   // Bs[k][n]

    int tid = threadIdx.x;
    int m0 = blockIdx.x * BM;
    int n0 = blockIdx.y * BN;
    int tx = tid & 15, ty = tid >> 4;

    // A-load: row = tid/2 (0..127), col = (tid&1)*4
    int arow = tid >> 1;
    int acol = (tid & 1) * 4;
    // B-load: row = tid/32 (0..7), col = (tid&31)*4
    int brow = tid >> 5;
    int bcol = (tid & 31) * 4;

    float acc[8][8];
#pragma unroll
    for (int i = 0; i < 8; ++i)
#pragma unroll
        for (int j = 0; j < 8; ++j) acc[i][j] = 0.f;

    for (int k0 = 0; k0 < K; k0 += BK) {
        int gm = m0 + arow;
        float4 av = make_float4(0.f, 0.f, 0.f, 0.f);
        if (gm < M) av = *(const float4*)&A[(size_t)gm * K + k0 + acol];
        As[acol + 0][arow] = av.x;
        As[acol + 1][arow] = av.y;
        As[acol + 2][arow] = av.z;
        As[acol + 3][arow] = av.w;

        float4 bv = *(const float4*)&B[(size_t)(k0 + brow) * NN + n0 + bcol];
        *(float4*)&Bs[brow][bcol] = bv;
        __syncthreads();

#pragma unroll
        for (int kk = 0; kk < BK; ++kk) {
            float a[8], b[8];
            *(float4*)&a[0] = *(float4*)&As[kk][ty * 4];
            *(float4*)&a[4] = *(float4*)&As[kk][64 + ty * 4];
            *(float4*)&b[0] = *(float4*)&Bs[kk][tx * 4];
            *(float4*)&b[4] = *(float4*)&Bs[kk][64 + tx * 4];
#pragma unroll
            for (int i = 0; i < 8; ++i)
#pragma unroll
                for (int j = 0; j < 8; ++j) acc[i][j] += a[i] * b[j];
        }
        __syncthreads();
    }

    // write back
#pragma unroll
    for (int i = 0; i < 8; ++i) {
        int row = m0 + ((i < 4) ? (ty * 4 + i) : (64 + ty * 4 + i - 4));
        if (row < M) {
            float4 c0 = make_float4(acc[i][0], acc[i][1], acc[i][2], acc[i][3]);
            float4 c1 = make_float4(acc[i][4], acc[i][5], acc[i][6], acc[i][7]);
            *(float4*)&C[(size_t)row * NN + n0 + tx * 4]      = c0;
            *(float4*)&C[(size_t)row * NN + n0 + 64 + tx * 4] = c1;
        }
    }
}

// ---------------------------------------------------------------------------
// Aggregation: one wave per node.  lane handles 8 contiguous channels.
// h[n] = relu( sum_{e: dst=e->n} hw[src_e]*dis[src]*dis[n] + hw[n]*dis[n]^2 + b )
// ---------------------------------------------------------------------------
__global__ __launch_bounds__(256) void agg_relu(const float* __restrict__ hw,
                                                const int* __restrict__ csr,
                                                const int* __restrict__ offs,
                                                const float* __restrict__ dis,
                                                const float* __restrict__ bias,
                                                float* __restrict__ out, int N) {
    int node = blockIdx.x * 4 + (threadIdx.x >> 6);
    if (node >= N) return;
    int lane = threadIdx.x & 63;
    int c0 = lane * 8;

    float dn = dis[node];
    float dis2 = dn * dn;

    float acc[8];
    float4 s0 = *(const float4*)&hw[(size_t)node * HID + c0];
    float4 s1 = *(const float4*)&hw[(size_t)node * HID + c0 + 4];
    acc[0] = s0.x * dis2 + bias[c0 + 0];
    acc[1] = s0.y * dis2 + bias[c0 + 1];
    acc[2] = s0.z * dis2 + bias[c0 + 2];
    acc[3] = s0.w * dis2 + bias[c0 + 3];
    acc[4] = s1.x * dis2 + bias[c0 + 4];
    acc[5] = s1.y * dis2 + bias[c0 + 5];
    acc[6] = s1.z * dis2 + bias[c0 + 6];
    acc[7] = s1.w * dis2 + bias[c0 + 7];

    int e0 = offs[node], e1 = offs[node + 1];
    for (int e = e0; e < e1; ++e) {
        int s = csr[e];
        float w = dis[s] * dn;
        float4 g0 = *(const float4*)&hw[(size_t)s * HID + c0];
        float4 g1 = *(const float4*)&hw[(size_t)s * HID + c0 + 4];
        acc[0] += g0.x * w; acc[1] += g0.y * w; acc[2] += g0.z * w; acc[3] += g0.w * w;
        acc[4] += g1.x * w; acc[5] += g1.y * w; acc[6] += g1.z * w; acc[7] += g1.w * w;
    }

    float4 o0 = make_float4(fmaxf(acc[0], 0.f), fmaxf(acc[1], 0.f), fmaxf(acc[2], 0.f), fmaxf(acc[3], 0.f));
    float4 o1 = make_float4(fmaxf(acc[4], 0.f), fmaxf(acc[5], 0.f), fmaxf(acc[6], 0.f), fmaxf(acc[7], 0.f));
    *(float4*)&out[(size_t)node * HID + c0]     = o0;
    *(float4*)&out[(size_t)node * HID + c0 + 4] = o1;
}

// Layer-2 aggregation with fused heads: h2 never materialized.
__global__ __launch_bounds__(256) void agg_relu_heads(const float* __restrict__ hw,
                                                      const int* __restrict__ csr,
                                                      const int* __restrict__ offs,
                                                      const float* __restrict__ dis,
                                                      const float* __restrict__ bias,
                                                      const float* __restrict__ Wo,
                                                      const float* __restrict__ bo,
                                                      const float* __restrict__ Ww,
                                                      const float* __restrict__ bw,
                                                      float* __restrict__ out, int N) {
    int node = blockIdx.x * 4 + (threadIdx.x >> 6);
    if (node >= N) return;
    int lane = threadIdx.x & 63;
    int c0 = lane * 8;

    float dn = dis[node];
    float dis2 = dn * dn;

    float acc[8];
    float4 s0 = *(const float4*)&hw[(size_t)node * HID + c0];
    float4 s1 = *(const float4*)&hw[(size_t)node * HID + c0 + 4];
    acc[0] = s0.x * dis2 + bias[c0 + 0];
    acc[1] = s0.y * dis2 + bias[c0 + 1];
    acc[2] = s0.z * dis2 + bias[c0 + 2];
    acc[3] = s0.w * dis2 + bias[c0 + 3];
    acc[4] = s1.x * dis2 + bias[c0 + 4];
    acc[5] = s1.y * dis2 + bias[c0 + 5];
    acc[6] = s1.z * dis2 + bias[c0 + 6];
    acc[7] = s1.w * dis2 + bias[c0 + 7];

    int e0 = offs[node], e1 = offs[node + 1];
    for (int e = e0; e < e1; ++e) {
        int s = csr[e];
        float w = dis[s] * dn;
        float4 g0 = *(const float4*)&hw[(size_t)s * HID + c0];
        float4 g1 = *(const float4*)&hw[(size_t)s * HID + c0 + 4];
        acc[0] += g0.x * w; acc[1] += g0.y * w; acc[2] += g0.z * w; acc[3] += g0.w * w;
        acc[4] += g1.x * w; acc[5] += g1.y * w; acc[6] += g1.z * w; acc[7] += g1.w * w;
    }

    float po = 0.f, pw = 0.f;
    float4 wo0 = *(const float4*)&Wo[c0];
    float4 wo1 = *(const float4*)&Wo[c0 + 4];
    float4 ww0 = *(const float4*)&Ww[c0];
    float4 ww1 = *(const float4*)&Ww[c0 + 4];
    float h;
    h = fmaxf(acc[0], 0.f); po += h * wo0.x; pw += h * ww0.x;
    h = fmaxf(acc[1], 0.f); po += h * wo0.y; pw += h * ww0.y;
    h = fmaxf(acc[2], 0.f); po += h * wo0.z; pw += h * ww0.z;
    h = fmaxf(acc[3], 0.f); po += h * wo0.w; pw += h * ww0.w;
    h = fmaxf(acc[4], 0.f); po += h * wo1.x; pw += h * ww1.x;
    h = fmaxf(acc[5], 0.f); po += h * wo1.y; pw += h * ww1.y;
    h = fmaxf(acc[6], 0.f); po += h * wo1.z; pw += h * ww1.z;
    h = fmaxf(acc[7], 0.f); po += h * wo1.w; pw += h * ww1.w;

    // wave-wide reduce (width 64)
#pragma unroll
    for (int off = 32; off > 0; off >>= 1) {
        po += __shfl_down(po, off);
        pw += __shfl_down(pw, off);
    }
    if (lane == 0) {
        out[node]     = po + bo[0];
        out[N + node] = pw + bw[0];
    }
}

// ---------------------------------------------------------------------------
extern "C" void kernel_launch(void* const* d_in, const int* in_sizes, int n_in,
                              void* d_out, int out_size, void* d_ws, size_t ws_size,
                              hipStream_t stream) {
    const float* x  = (const float*)d_in[0];
    const int*   ei = (const int*)d_in[1];
    const float* W1 = (const float*)d_in[2];
    const float* b1 = (const float*)d_in[3];
    const float* W2 = (const float*)d_in[4];
    const float* b2 = (const float*)d_in[5];
    const float* Wo = (const float*)d_in[6];
    const float* bo = (const float*)d_in[7];
    const float* Ww = (const float*)d_in[8];
    const float* bw = (const float*)d_in[9];

    const int N = in_sizes[0] / DIN;   // 25000
    const int E = in_sizes[1] / 2;     // 200000

    // workspace carve-up (256B aligned)
    char* ws = (char*)d_ws;
    size_t p = 0;
    auto alloc = [&](size_t bytes) -> char* {
        char* r = ws + p;
        p += (bytes + 255) & ~(size_t)255;
        return r;
    };
    int*   cnt    = (int*)alloc((size_t)N * 4);
    int*   offs   = (int*)alloc((size_t)(N + 1) * 4);
    int*   cursor = (int*)alloc((size_t)N * 4);
    float* dis    = (float*)alloc((size_t)N * 4);
    int*   csr    = (int*)alloc((size_t)E * 4);
    float* hw     = (float*)alloc((size_t)N * HID * 4);
    float* h1     = (float*)alloc((size_t)N * HID * 4);

    const int* src = ei;
    const int* dst = ei + E;

    hipMemsetAsync(cnt, 0, (size_t)N * 4, stream);
    hipMemsetAsync(cursor, 0, (size_t)N * 4, stream);

    count_kernel<<<(E + 255) / 256, 256, 0, stream>>>(dst, cnt, E);
    scan_kernel<<<1, 1024, 0, stream>>>(cnt, offs, dis, N);
    fill_kernel<<<(E + 255) / 256, 256, 0, stream>>>(src, dst, offs, cursor, csr, E);

    dim3 ggrid((N + BM - 1) / BM, HID / BN);
    // layer 1
    gemm_f32<<<ggrid, 256, 0, stream>>>(x, W1, hw, N);
    agg_relu<<<(N + 3) / 4, 256, 0, stream>>>(hw, csr, offs, dis, b1, h1, N);
    // layer 2
    gemm_f32<<<ggrid, 256, 0, stream>>>(h1, W2, hw, N);
    agg_relu_heads<<<(N + 3) / 4, 256, 0, stream>>>(hw, csr, offs, dis, b2,
                                                    Wo, bo, Ww, bw, (float*)d_out, N);
}

// Round 2
// 280.083 us; speedup vs baseline: 2.4125x; 2.4125x over previous
//
#include <hip/hip_runtime.h>
#include <hip/hip_bf16.h>

#define DIN 512
#define HID 512

#define AS1 __attribute__((address_space(1)))
#define AS3 __attribute__((address_space(3)))

typedef __attribute__((ext_vector_type(8))) short bfrag;     // 8 bf16 (4 VGPRs)
typedef __attribute__((ext_vector_type(4))) float ffrag;     // 4 fp32 acc
typedef __attribute__((ext_vector_type(8))) unsigned short u16x8;

// ---------------------------------------------------------------------------
// CSR build
// ---------------------------------------------------------------------------
__global__ void count_kernel(const int* __restrict__ dst, int* __restrict__ cnt, int E) {
    int e = blockIdx.x * 256 + threadIdx.x;
    if (e >= E) return;
    atomicAdd(&cnt[dst[e]], 1);
}

// 3-stage scan: per-block wave-shuffle scan, block-sum scan, fixup.
__global__ __launch_bounds__(256) void scan1(const int* __restrict__ cnt, int* __restrict__ tmp,
                                             int* __restrict__ bsum, int N) {
    int tid = threadIdx.x, lane = tid & 63, wave = tid >> 6;
    int i = blockIdx.x * 256 + tid;
    int v = (i < N) ? cnt[i] : 0;
    int incl = v;
#pragma unroll
    for (int o = 1; o < 64; o <<= 1) {
        int t = __shfl_up(incl, o);
        if (lane >= o) incl += t;
    }
    __shared__ int wtot[4];
    if (lane == 63) wtot[wave] = incl;
    __syncthreads();
    int woff = 0;
#pragma unroll
    for (int w = 0; w < 4; ++w) woff += (w < wave) ? wtot[w] : 0;
    if (i < N) tmp[i] = woff + incl - v;   // block-local exclusive
    if (tid == 255) bsum[blockIdx.x] = woff + incl;
}

__global__ void scan2(int* __restrict__ bsum, int nb) {
    int tid = threadIdx.x;  // 128 threads, nb <= 128
    int lane = tid & 63, wave = tid >> 6;
    int v = (tid < nb) ? bsum[tid] : 0;
    int incl = v;
#pragma unroll
    for (int o = 1; o < 64; o <<= 1) {
        int t = __shfl_up(incl, o);
        if (lane >= o) incl += t;
    }
    __shared__ int w0;
    if (tid == 63) w0 = incl;
    __syncthreads();
    int off = wave ? w0 : 0;
    if (tid < nb) bsum[tid] = off + incl - v;  // exclusive
    if (tid == 127) bsum[nb] = off + incl;     // grand total
}

__global__ void scan3(const int* __restrict__ cnt, const int* __restrict__ tmp,
                      const int* __restrict__ bsum, int* __restrict__ offs,
                      float* __restrict__ dis, int N, int nb) {
    int i = blockIdx.x * 256 + threadIdx.x;
    if (i < N) {
        offs[i] = tmp[i] + bsum[i >> 8];
        dis[i] = rsqrtf((float)cnt[i] + 1.0f);
    }
    if (i == 0) offs[N] = bsum[nb];
}

__global__ void fill_kernel(const int* __restrict__ src, const int* __restrict__ dst,
                            const int* __restrict__ offs, int* __restrict__ cursor,
                            int* __restrict__ csr, int E) {
    int e = blockIdx.x * 256 + threadIdx.x;
    if (e >= E) return;
    int d = dst[e];
    int pos = offs[d] + atomicAdd(&cursor[d], 1);
    csr[pos] = src[e];
}

// ---------------------------------------------------------------------------
// fp32 -> bf16 conversions
// ---------------------------------------------------------------------------
// x [N,512] fp32 -> xb [Mpad,512] bf16, pad rows zeroed. One thread = 8 elems.
__global__ __launch_bounds__(256) void convert_pad(const float* __restrict__ x,
                                                   unsigned short* __restrict__ xb,
                                                   int Nvalid) {
    int idx = blockIdx.x * 256 + threadIdx.x;      // over Mpad*64
    int row = idx >> 6;
    int c = (idx & 63) * 8;
    unsigned short o[8];
    if (row < Nvalid) {
        float4 a = *(const float4*)&x[(size_t)row * 512 + c];
        float4 b = *(const float4*)&x[(size_t)row * 512 + c + 4];
        __hip_bfloat16 t;
        t = __float2bfloat16(a.x); o[0] = *(unsigned short*)&t;
        t = __float2bfloat16(a.y); o[1] = *(unsigned short*)&t;
        t = __float2bfloat16(a.z); o[2] = *(unsigned short*)&t;
        t = __float2bfloat16(a.w); o[3] = *(unsigned short*)&t;
        t = __float2bfloat16(b.x); o[4] = *(unsigned short*)&t;
        t = __float2bfloat16(b.y); o[5] = *(unsigned short*)&t;
        t = __float2bfloat16(b.z); o[6] = *(unsigned short*)&t;
        t = __float2bfloat16(b.w); o[7] = *(unsigned short*)&t;
    } else {
#pragma unroll
        for (int j = 0; j < 8; ++j) o[j] = 0;
    }
    *(u16x8*)&xb[(size_t)row * 512 + c] = *(u16x8*)o;
}

// W [K=512][N=512] fp32 -> Wt [N][K] bf16 (transposed so K is contiguous)
__global__ void transpose_cvt(const float* __restrict__ W, unsigned short* __restrict__ Wt) {
    __shared__ float t[32][33];
    int tx = threadIdx.x, ty = threadIdx.y;       // 32 x 8
    int n0 = blockIdx.x * 32, k0 = blockIdx.y * 32;
#pragma unroll
    for (int s = 0; s < 4; ++s)
        t[ty + 8 * s][tx] = W[(size_t)(k0 + ty + 8 * s) * 512 + n0 + tx];
    __syncthreads();
#pragma unroll
    for (int s = 0; s < 4; ++s) {
        __hip_bfloat16 b = __float2bfloat16(t[tx][ty + 8 * s]);
        Wt[(size_t)(n0 + ty + 8 * s) * 512 + k0 + tx] = *(unsigned short*)&b;
    }
}

// ---------------------------------------------------------------------------
// bf16 MFMA GEMM: C[Mpad,512](bf16) = A[Mpad,512](bf16) @ Wt^T
//   A row-major k-contig; Wt is [n][k] (k-contig).  128x128 tile, BK=64.
//   256 threads = 4 waves in 2x2; each wave 64x64 via 4x4 of 16x16x32 MFMA.
//   Staging via global_load_lds width=16 with XOR-8 chunk swizzle (kills the
//   4-way ds_read_b128 bank conflict while respecting the wave-uniform-base
//   + lane*16 LDS landing constraint).
// ---------------------------------------------------------------------------
__global__ __launch_bounds__(256) void gemm_bf16(const short* __restrict__ A,
                                                 const short* __restrict__ B,
                                                 unsigned short* __restrict__ C) {
    __shared__ __align__(16) short As[128 * 64];   // 16 KB, row-major [m][k], swizzled chunks
    __shared__ __align__(16) short Bs[128 * 64];   // 16 KB, [n][k]
    const int K = 512;
    int tid = threadIdx.x;
    int lane = tid & 63, wave = tid >> 6;
    int m0 = blockIdx.x * 128;
    int n0 = blockIdx.y * 128;
    int wm = (wave & 1) * 64;
    int wn = (wave >> 1) * 64;
    int r = lane & 15, q = lane >> 4;

    // staging addresses: slot s = issue*256 + tid; row = s>>3; chunk = (s&7)^(row&7)
    size_t aglob[4], bglob[4];
    int ldsoff[4];
#pragma unroll
    for (int i = 0; i < 4; ++i) {
        int s = i * 256 + tid;
        int row = s >> 3;
        int c = (s & 7) ^ (row & 7);
        aglob[i] = (size_t)(m0 + row) * K + c * 8;
        bglob[i] = (size_t)(n0 + row) * K + c * 8;
        ldsoff[i] = (i * 256 + (tid & ~63)) * 8;   // wave-uniform slot base, in shorts
    }

    ffrag acc[4][4];
#pragma unroll
    for (int i = 0; i < 4; ++i)
#pragma unroll
        for (int j = 0; j < 4; ++j) acc[i][j] = ffrag{0.f, 0.f, 0.f, 0.f};

    for (int k0 = 0; k0 < K; k0 += 64) {
#pragma unroll
        for (int i = 0; i < 4; ++i) {
            __builtin_amdgcn_global_load_lds((const AS1 void*)(A + aglob[i] + k0),
                                             (AS3 void*)(As + ldsoff[i]), 16, 0, 0);
            __builtin_amdgcn_global_load_lds((const AS1 void*)(B + bglob[i] + k0),
                                             (AS3 void*)(Bs + ldsoff[i]), 16, 0, 0);
        }
        __syncthreads();   // compiler emits vmcnt(0) drain before barrier

#pragma unroll
        for (int s2 = 0; s2 < 2; ++s2) {
            bfrag af[4], bfr[4];
#pragma unroll
            for (int i = 0; i < 4; ++i) {
                int arow = wm + i * 16 + r;
                int ach = (s2 * 4 + q) ^ (arow & 7);
                af[i] = *(const bfrag*)&As[arow * 64 + ach * 8];
                int brow = wn + i * 16 + r;
                int bch = (s2 * 4 + q) ^ (brow & 7);
                bfr[i] = *(const bfrag*)&Bs[brow * 64 + bch * 8];
            }
#pragma unroll
            for (int i = 0; i < 4; ++i)
#pragma unroll
                for (int j = 0; j < 4; ++j)
                    acc[i][j] = __builtin_amdgcn_mfma_f32_16x16x32_bf16(af[i], bfr[j], acc[i][j], 0, 0, 0);
        }
        __syncthreads();
    }

    // epilogue: C/D layout col=lane&15, row=q*4+reg; store bf16
#pragma unroll
    for (int i = 0; i < 4; ++i)
#pragma unroll
        for (int j = 0; j < 4; ++j)
#pragma unroll
            for (int reg = 0; reg < 4; ++reg) {
                int row = m0 + wm + i * 16 + q * 4 + reg;
                int col = n0 + wn + j * 16 + r;
                __hip_bfloat16 b = __float2bfloat16(acc[i][j][reg]);
                C[(size_t)row * 512 + col] = *(unsigned short*)&b;
            }
}

// ---------------------------------------------------------------------------
// Aggregation (bf16 in / bf16 out): one wave per node, lane = 8 channels.
// ---------------------------------------------------------------------------
__device__ inline void ld_bf16x8(const unsigned short* p, float* f) {
    u16x8 v = *(const u16x8*)p;
#pragma unroll
    for (int j = 0; j < 8; ++j) f[j] = __uint_as_float((unsigned)v[j] << 16);
}

__global__ __launch_bounds__(256) void agg_relu(const unsigned short* __restrict__ hw,
                                                const int* __restrict__ csr,
                                                const int* __restrict__ offs,
                                                const float* __restrict__ dis,
                                                const float* __restrict__ bias,
                                                unsigned short* __restrict__ out, int N) {
    int node = blockIdx.x * 4 + (threadIdx.x >> 6);
    if (node >= N) return;
    int lane = threadIdx.x & 63;
    int c0 = lane * 8;

    float dn = dis[node];
    float dis2 = dn * dn;

    float acc[8], g[8];
    ld_bf16x8(&hw[(size_t)node * HID + c0], g);
    float4 bb0 = *(const float4*)&bias[c0];
    float4 bb1 = *(const float4*)&bias[c0 + 4];
    acc[0] = g[0] * dis2 + bb0.x; acc[1] = g[1] * dis2 + bb0.y;
    acc[2] = g[2] * dis2 + bb0.z; acc[3] = g[3] * dis2 + bb0.w;
    acc[4] = g[4] * dis2 + bb1.x; acc[5] = g[5] * dis2 + bb1.y;
    acc[6] = g[6] * dis2 + bb1.z; acc[7] = g[7] * dis2 + bb1.w;

    int e0 = offs[node], e1 = offs[node + 1];
    for (int e = e0; e < e1; ++e) {
        int s = csr[e];
        float w = dis[s] * dn;
        ld_bf16x8(&hw[(size_t)s * HID + c0], g);
#pragma unroll
        for (int j = 0; j < 8; ++j) acc[j] += g[j] * w;
    }

    unsigned short o[8];
#pragma unroll
    for (int j = 0; j < 8; ++j) {
        __hip_bfloat16 b = __float2bfloat16(fmaxf(acc[j], 0.f));
        o[j] = *(unsigned short*)&b;
    }
    *(u16x8*)&out[(size_t)node * HID + c0] = *(u16x8*)o;
}

__global__ __launch_bounds__(256) void agg_relu_heads(const unsigned short* __restrict__ hw,
                                                      const int* __restrict__ csr,
                                                      const int* __restrict__ offs,
                                                      const float* __restrict__ dis,
                                                      const float* __restrict__ bias,
                                                      const float* __restrict__ Wo,
                                                      const float* __restrict__ bo,
                                                      const float* __restrict__ Ww,
                                                      const float* __restrict__ bw,
                                                      float* __restrict__ out, int N) {
    int node = blockIdx.x * 4 + (threadIdx.x >> 6);
    if (node >= N) return;
    int lane = threadIdx.x & 63;
    int c0 = lane * 8;

    float dn = dis[node];
    float dis2 = dn * dn;

    float acc[8], g[8];
    ld_bf16x8(&hw[(size_t)node * HID + c0], g);
    float4 bb0 = *(const float4*)&bias[c0];
    float4 bb1 = *(const float4*)&bias[c0 + 4];
    acc[0] = g[0] * dis2 + bb0.x; acc[1] = g[1] * dis2 + bb0.y;
    acc[2] = g[2] * dis2 + bb0.z; acc[3] = g[3] * dis2 + bb0.w;
    acc[4] = g[4] * dis2 + bb1.x; acc[5] = g[5] * dis2 + bb1.y;
    acc[6] = g[6] * dis2 + bb1.z; acc[7] = g[7] * dis2 + bb1.w;

    int e0 = offs[node], e1 = offs[node + 1];
    for (int e = e0; e < e1; ++e) {
        int s = csr[e];
        float w = dis[s] * dn;
        ld_bf16x8(&hw[(size_t)s * HID + c0], g);
#pragma unroll
        for (int j = 0; j < 8; ++j) acc[j] += g[j] * w;
    }

    float4 wo0 = *(const float4*)&Wo[c0];
    float4 wo1 = *(const float4*)&Wo[c0 + 4];
    float4 ww0 = *(const float4*)&Ww[c0];
    float4 ww1 = *(const float4*)&Ww[c0 + 4];
    float po = 0.f, pw = 0.f, h;
    h = fmaxf(acc[0], 0.f); po += h * wo0.x; pw += h * ww0.x;
    h = fmaxf(acc[1], 0.f); po += h * wo0.y; pw += h * ww0.y;
    h = fmaxf(acc[2], 0.f); po += h * wo0.z; pw += h * ww0.z;
    h = fmaxf(acc[3], 0.f); po += h * wo0.w; pw += h * ww0.w;
    h = fmaxf(acc[4], 0.f); po += h * wo1.x; pw += h * ww1.x;
    h = fmaxf(acc[5], 0.f); po += h * wo1.y; pw += h * ww1.y;
    h = fmaxf(acc[6], 0.f); po += h * wo1.z; pw += h * ww1.z;
    h = fmaxf(acc[7], 0.f); po += h * wo1.w; pw += h * ww1.w;

#pragma unroll
    for (int off = 32; off > 0; off >>= 1) {
        po += __shfl_down(po, off);
        pw += __shfl_down(pw, off);
    }
    if (lane == 0) {
        out[node]     = po + bo[0];
        out[N + node] = pw + bw[0];
    }
}

// ---------------------------------------------------------------------------
extern "C" void kernel_launch(void* const* d_in, const int* in_sizes, int n_in,
                              void* d_out, int out_size, void* d_ws, size_t ws_size,
                              hipStream_t stream) {
    const float* x  = (const float*)d_in[0];
    const int*   ei = (const int*)d_in[1];
    const float* W1 = (const float*)d_in[2];
    const float* b1 = (const float*)d_in[3];
    const float* W2 = (const float*)d_in[4];
    const float* b2 = (const float*)d_in[5];
    const float* Wo = (const float*)d_in[6];
    const float* bo = (const float*)d_in[7];
    const float* Ww = (const float*)d_in[8];
    const float* bw = (const float*)d_in[9];

    const int N = in_sizes[0] / DIN;           // 25000
    const int E = in_sizes[1] / 2;             // 200000
    const int Mpad = (N + 127) & ~127;         // 25088
    const int nb = (N + 255) / 256;            // 98

    char* ws = (char*)d_ws;
    size_t p = 0;
    auto alloc = [&](size_t bytes) -> char* {
        char* r = ws + p;
        p += (bytes + 255) & ~(size_t)255;
        return r;
    };
    int*   cnt    = (int*)alloc((size_t)N * 4);
    int*   offs   = (int*)alloc((size_t)(N + 1) * 4);
    int*   cursor = (int*)alloc((size_t)N * 4);
    int*   tmp    = (int*)alloc((size_t)N * 4);
    int*   bsum   = (int*)alloc(132 * 4);
    float* dis    = (float*)alloc((size_t)N * 4);
    int*   csr    = (int*)alloc((size_t)E * 4);
    unsigned short* xb  = (unsigned short*)alloc((size_t)Mpad * 512 * 2);
    unsigned short* Wt1 = (unsigned short*)alloc((size_t)512 * 512 * 2);
    unsigned short* Wt2 = (unsigned short*)alloc((size_t)512 * 512 * 2);
    unsigned short* hw  = (unsigned short*)alloc((size_t)Mpad * 512 * 2);
    unsigned short* h1  = (unsigned short*)alloc((size_t)Mpad * 512 * 2);

    const int* src = ei;
    const int* dst = ei + E;

    hipMemsetAsync(cnt, 0, (size_t)N * 4, stream);
    hipMemsetAsync(cursor, 0, (size_t)N * 4, stream);
    if (Mpad > N)  // zero h1 pad rows (read by layer-2 GEMM)
        hipMemsetAsync(h1 + (size_t)N * 512, 0, (size_t)(Mpad - N) * 512 * 2, stream);

    count_kernel<<<(E + 255) / 256, 256, 0, stream>>>(dst, cnt, E);
    scan1<<<nb, 256, 0, stream>>>(cnt, tmp, bsum, N);
    scan2<<<1, 128, 0, stream>>>(bsum, nb);
    scan3<<<nb, 256, 0, stream>>>(cnt, tmp, bsum, offs, dis, N, nb);
    fill_kernel<<<(E + 255) / 256, 256, 0, stream>>>(src, dst, offs, cursor, csr, E);

    convert_pad<<<(Mpad * 64) / 256, 256, 0, stream>>>(x, xb, N);
    transpose_cvt<<<dim3(16, 16), dim3(32, 8), 0, stream>>>(W1, Wt1);
    transpose_cvt<<<dim3(16, 16), dim3(32, 8), 0, stream>>>(W2, Wt2);

    dim3 ggrid(Mpad / 128, 4);
    gemm_bf16<<<ggrid, 256, 0, stream>>>((const short*)xb, (const short*)Wt1, hw);
    agg_relu<<<(N + 3) / 4, 256, 0, stream>>>(hw, csr, offs, dis, b1, h1, N);
    gemm_bf16<<<ggrid, 256, 0, stream>>>((const short*)h1, (const short*)Wt2, hw);
    agg_relu_heads<<<(N + 3) / 4, 256, 0, stream>>>(hw, csr, offs, dis, b2,
                                                    Wo, bo, Ww, bw, (float*)d_out, N);
}

// Round 3
// 263.024 us; speedup vs baseline: 2.5690x; 1.0649x over previous
//
#include <hip/hip_runtime.h>
#include <hip/hip_bf16.h>

#define DIN 512
#define HID 512

#define AS1 __attribute__((address_space(1)))
#define AS3 __attribute__((address_space(3)))

typedef __attribute__((ext_vector_type(8))) short bfrag;     // 8 bf16 (4 VGPRs)
typedef __attribute__((ext_vector_type(4))) float ffrag;     // 4 fp32 acc
typedef __attribute__((ext_vector_type(8))) unsigned short u16x8;
typedef __attribute__((ext_vector_type(4))) unsigned short u16x4;

// ---------------------------------------------------------------------------
// CSR build
// ---------------------------------------------------------------------------
__global__ void count_kernel(const int* __restrict__ dst, int* __restrict__ cnt, int E) {
    int e = blockIdx.x * 256 + threadIdx.x;
    if (e >= E) return;
    atomicAdd(&cnt[dst[e]], 1);
}

__global__ __launch_bounds__(256) void scan1(const int* __restrict__ cnt, int* __restrict__ tmp,
                                             int* __restrict__ bsum, int N) {
    int tid = threadIdx.x, lane = tid & 63, wave = tid >> 6;
    int i = blockIdx.x * 256 + tid;
    int v = (i < N) ? cnt[i] : 0;
    int incl = v;
#pragma unroll
    for (int o = 1; o < 64; o <<= 1) {
        int t = __shfl_up(incl, o);
        if (lane >= o) incl += t;
    }
    __shared__ int wtot[4];
    if (lane == 63) wtot[wave] = incl;
    __syncthreads();
    int woff = 0;
#pragma unroll
    for (int w = 0; w < 4; ++w) woff += (w < wave) ? wtot[w] : 0;
    if (i < N) tmp[i] = woff + incl - v;   // block-local exclusive
    if (tid == 255) bsum[blockIdx.x] = woff + incl;
}

__global__ void scan2(int* __restrict__ bsum, int nb) {
    int tid = threadIdx.x;  // 128 threads, nb <= 128
    int lane = tid & 63, wave = tid >> 6;
    int v = (tid < nb) ? bsum[tid] : 0;
    int incl = v;
#pragma unroll
    for (int o = 1; o < 64; o <<= 1) {
        int t = __shfl_up(incl, o);
        if (lane >= o) incl += t;
    }
    __shared__ int w0;
    if (tid == 63) w0 = incl;
    __syncthreads();
    int off = wave ? w0 : 0;
    if (tid < nb) bsum[tid] = off + incl - v;  // exclusive
    if (tid == 127) bsum[nb] = off + incl;     // grand total
}

__global__ void scan3(const int* __restrict__ cnt, const int* __restrict__ tmp,
                      const int* __restrict__ bsum, int* __restrict__ offs,
                      float* __restrict__ dis, int N, int nb) {
    int i = blockIdx.x * 256 + threadIdx.x;
    if (i < N) {
        offs[i] = tmp[i] + bsum[i >> 8];
        dis[i] = rsqrtf((float)cnt[i] + 1.0f);
    }
    if (i == 0) offs[N] = bsum[nb];
}

// fill CSR; also store sdis[pos] = dis[src] so agg has no dependent dis load
__global__ void fill_kernel(const int* __restrict__ src, const int* __restrict__ dst,
                            const int* __restrict__ offs, int* __restrict__ cursor,
                            const float* __restrict__ dis,
                            int* __restrict__ csr, float* __restrict__ sdis, int E) {
    int e = blockIdx.x * 256 + threadIdx.x;
    if (e >= E) return;
    int d = dst[e];
    int s = src[e];
    int pos = offs[d] + atomicAdd(&cursor[d], 1);
    csr[pos] = s;
    sdis[pos] = dis[s];
}

// ---------------------------------------------------------------------------
// fp32 -> bf16 conversions
// ---------------------------------------------------------------------------
__global__ __launch_bounds__(256) void convert_pad(const float* __restrict__ x,
                                                   unsigned short* __restrict__ xb,
                                                   int Nvalid) {
    int idx = blockIdx.x * 256 + threadIdx.x;      // over Mpad*64
    int row = idx >> 6;
    int c = (idx & 63) * 8;
    unsigned short o[8];
    if (row < Nvalid) {
        float4 a = *(const float4*)&x[(size_t)row * 512 + c];
        float4 b = *(const float4*)&x[(size_t)row * 512 + c + 4];
        __hip_bfloat16 t;
        t = __float2bfloat16(a.x); o[0] = *(unsigned short*)&t;
        t = __float2bfloat16(a.y); o[1] = *(unsigned short*)&t;
        t = __float2bfloat16(a.z); o[2] = *(unsigned short*)&t;
        t = __float2bfloat16(a.w); o[3] = *(unsigned short*)&t;
        t = __float2bfloat16(b.x); o[4] = *(unsigned short*)&t;
        t = __float2bfloat16(b.y); o[5] = *(unsigned short*)&t;
        t = __float2bfloat16(b.z); o[6] = *(unsigned short*)&t;
        t = __float2bfloat16(b.w); o[7] = *(unsigned short*)&t;
    } else {
#pragma unroll
        for (int j = 0; j < 8; ++j) o[j] = 0;
    }
    *(u16x8*)&xb[(size_t)row * 512 + c] = *(u16x8*)o;
}

__global__ void transpose_cvt(const float* __restrict__ W, unsigned short* __restrict__ Wt) {
    __shared__ float t[32][33];
    int tx = threadIdx.x, ty = threadIdx.y;       // 32 x 8
    int n0 = blockIdx.x * 32, k0 = blockIdx.y * 32;
#pragma unroll
    for (int s = 0; s < 4; ++s)
        t[ty + 8 * s][tx] = W[(size_t)(k0 + ty + 8 * s) * 512 + n0 + tx];
    __syncthreads();
#pragma unroll
    for (int s = 0; s < 4; ++s) {
        __hip_bfloat16 b = __float2bfloat16(t[tx][ty + 8 * s]);
        Wt[(size_t)(n0 + ty + 8 * s) * 512 + k0 + tx] = *(unsigned short*)&b;
    }
}

// ---------------------------------------------------------------------------
// bf16 MFMA GEMM: C[Mpad,512](bf16) = A[Mpad,512](bf16) @ Wt^T
//   Operand-SWAPPED mfma: acc holds C^T-fragments, so each lane's 4 regs are
//   4 consecutive C-columns -> packed 8-B stores in the epilogue.
// ---------------------------------------------------------------------------
__global__ __launch_bounds__(256) void gemm_bf16(const short* __restrict__ A,
                                                 const short* __restrict__ B,
                                                 unsigned short* __restrict__ C) {
    __shared__ __align__(16) short As[128 * 64];   // 16 KB, [m][k], XOR-swizzled chunks
    __shared__ __align__(16) short Bs[128 * 64];   // 16 KB, [n][k]
    const int K = 512;
    int tid = threadIdx.x;
    int lane = tid & 63, wave = tid >> 6;
    int m0 = blockIdx.x * 128;
    int n0 = blockIdx.y * 128;
    int wm = (wave & 1) * 64;
    int wn = (wave >> 1) * 64;
    int r = lane & 15, q = lane >> 4;

    size_t aglob[4], bglob[4];
    int ldsoff[4];
#pragma unroll
    for (int i = 0; i < 4; ++i) {
        int s = i * 256 + tid;
        int row = s >> 3;
        int c = (s & 7) ^ (row & 7);
        aglob[i] = (size_t)(m0 + row) * K + c * 8;
        bglob[i] = (size_t)(n0 + row) * K + c * 8;
        ldsoff[i] = (i * 256 + (tid & ~63)) * 8;   // wave-uniform slot base, in shorts
    }

    ffrag acc[4][4];
#pragma unroll
    for (int i = 0; i < 4; ++i)
#pragma unroll
        for (int j = 0; j < 4; ++j) acc[i][j] = ffrag{0.f, 0.f, 0.f, 0.f};

    for (int k0 = 0; k0 < K; k0 += 64) {
#pragma unroll
        for (int i = 0; i < 4; ++i) {
            __builtin_amdgcn_global_load_lds((const AS1 void*)(A + aglob[i] + k0),
                                             (AS3 void*)(As + ldsoff[i]), 16, 0, 0);
            __builtin_amdgcn_global_load_lds((const AS1 void*)(B + bglob[i] + k0),
                                             (AS3 void*)(Bs + ldsoff[i]), 16, 0, 0);
        }
        __syncthreads();

#pragma unroll
        for (int s2 = 0; s2 < 2; ++s2) {
            bfrag af[4], bfr[4];
#pragma unroll
            for (int i = 0; i < 4; ++i) {
                int arow = wm + i * 16 + r;
                int ach = (s2 * 4 + q) ^ (arow & 7);
                af[i] = *(const bfrag*)&As[arow * 64 + ach * 8];
                int brow = wn + i * 16 + r;
                int bch = (s2 * 4 + q) ^ (brow & 7);
                bfr[i] = *(const bfrag*)&Bs[brow * 64 + bch * 8];
            }
            // swapped: D' = B^T * A^T = C^T fragments
#pragma unroll
            for (int i = 0; i < 4; ++i)
#pragma unroll
                for (int j = 0; j < 4; ++j)
                    acc[i][j] = __builtin_amdgcn_mfma_f32_16x16x32_bf16(bfr[j], af[i], acc[i][j], 0, 0, 0);
        }
        __syncthreads();
    }

    // epilogue: lane holds C[m = i*16 + r][n = j*16 + q*4 + reg] -> 8-B stores
#pragma unroll
    for (int i = 0; i < 4; ++i) {
        int m = m0 + wm + i * 16 + r;
#pragma unroll
        for (int j = 0; j < 4; ++j) {
            int n = n0 + wn + j * 16 + q * 4;
            u16x4 o;
#pragma unroll
            for (int reg = 0; reg < 4; ++reg) {
                __hip_bfloat16 b = __float2bfloat16(acc[i][j][reg]);
                o[reg] = *(unsigned short*)&b;
            }
            *(u16x4*)&C[(size_t)m * 512 + n] = o;
        }
    }
}

// ---------------------------------------------------------------------------
// Aggregation: one wave per node, lane = 8 channels. Batch-4 edge gathers
// for 4x memory-level parallelism; sdis[] removes the dependent dis load.
// ---------------------------------------------------------------------------
__device__ inline void cvt8(u16x8 v, float* f) {
#pragma unroll
    for (int j = 0; j < 8; ++j) f[j] = __uint_as_float((unsigned)v[j] << 16);
}

__global__ __launch_bounds__(256) void agg_relu(const unsigned short* __restrict__ hw,
                                                const int* __restrict__ csr,
                                                const float* __restrict__ sdis,
                                                const int* __restrict__ offs,
                                                const float* __restrict__ dis,
                                                const float* __restrict__ bias,
                                                unsigned short* __restrict__ out, int N) {
    int node = blockIdx.x * 4 + (threadIdx.x >> 6);
    if (node >= N) return;
    int lane = threadIdx.x & 63;
    int c0 = lane * 8;

    float dn = dis[node];
    int e0 = offs[node], e1 = offs[node + 1];

    float acc[8];
    {
        u16x8 sv = *(const u16x8*)&hw[(size_t)node * HID + c0];
        float g[8];
        cvt8(sv, g);
        float4 bb0 = *(const float4*)&bias[c0];
        float4 bb1 = *(const float4*)&bias[c0 + 4];
        float dis2 = dn * dn;
        acc[0] = g[0] * dis2 + bb0.x; acc[1] = g[1] * dis2 + bb0.y;
        acc[2] = g[2] * dis2 + bb0.z; acc[3] = g[3] * dis2 + bb0.w;
        acc[4] = g[4] * dis2 + bb1.x; acc[5] = g[5] * dis2 + bb1.y;
        acc[6] = g[6] * dis2 + bb1.z; acc[7] = g[7] * dis2 + bb1.w;
    }

    int e = e0;
    for (; e + 4 <= e1; e += 4) {
        int s0 = csr[e], s1 = csr[e + 1], s2 = csr[e + 2], s3 = csr[e + 3];
        float w0 = sdis[e] * dn, w1 = sdis[e + 1] * dn;
        float w2 = sdis[e + 2] * dn, w3 = sdis[e + 3] * dn;
        u16x8 v0 = *(const u16x8*)&hw[(size_t)s0 * HID + c0];
        u16x8 v1 = *(const u16x8*)&hw[(size_t)s1 * HID + c0];
        u16x8 v2 = *(const u16x8*)&hw[(size_t)s2 * HID + c0];
        u16x8 v3 = *(const u16x8*)&hw[(size_t)s3 * HID + c0];
        float g[8];
        cvt8(v0, g);
#pragma unroll
        for (int j = 0; j < 8; ++j) acc[j] += g[j] * w0;
        cvt8(v1, g);
#pragma unroll
        for (int j = 0; j < 8; ++j) acc[j] += g[j] * w1;
        cvt8(v2, g);
#pragma unroll
        for (int j = 0; j < 8; ++j) acc[j] += g[j] * w2;
        cvt8(v3, g);
#pragma unroll
        for (int j = 0; j < 8; ++j) acc[j] += g[j] * w3;
    }
    for (; e < e1; ++e) {
        int s = csr[e];
        float w = sdis[e] * dn;
        u16x8 v = *(const u16x8*)&hw[(size_t)s * HID + c0];
        float g[8];
        cvt8(v, g);
#pragma unroll
        for (int j = 0; j < 8; ++j) acc[j] += g[j] * w;
    }

    unsigned short o[8];
#pragma unroll
    for (int j = 0; j < 8; ++j) {
        __hip_bfloat16 b = __float2bfloat16(fmaxf(acc[j], 0.f));
        o[j] = *(unsigned short*)&b;
    }
    *(u16x8*)&out[(size_t)node * HID + c0] = *(u16x8*)o;
}

__global__ __launch_bounds__(256) void agg_relu_heads(const unsigned short* __restrict__ hw,
                                                      const int* __restrict__ csr,
                                                      const float* __restrict__ sdis,
                                                      const int* __restrict__ offs,
                                                      const float* __restrict__ dis,
                                                      const float* __restrict__ bias,
                                                      const float* __restrict__ Wo,
                                                      const float* __restrict__ bo,
                                                      const float* __restrict__ Ww,
                                                      const float* __restrict__ bw,
                                                      float* __restrict__ out, int N) {
    int node = blockIdx.x * 4 + (threadIdx.x >> 6);
    if (node >= N) return;
    int lane = threadIdx.x & 63;
    int c0 = lane * 8;

    float dn = dis[node];
    int e0 = offs[node], e1 = offs[node + 1];

    float acc[8];
    {
        u16x8 sv = *(const u16x8*)&hw[(size_t)node * HID + c0];
        float g[8];
        cvt8(sv, g);
        float4 bb0 = *(const float4*)&bias[c0];
        float4 bb1 = *(const float4*)&bias[c0 + 4];
        float dis2 = dn * dn;
        acc[0] = g[0] * dis2 + bb0.x; acc[1] = g[1] * dis2 + bb0.y;
        acc[2] = g[2] * dis2 + bb0.z; acc[3] = g[3] * dis2 + bb0.w;
        acc[4] = g[4] * dis2 + bb1.x; acc[5] = g[5] * dis2 + bb1.y;
        acc[6] = g[6] * dis2 + bb1.z; acc[7] = g[7] * dis2 + bb1.w;
    }

    int e = e0;
    for (; e + 4 <= e1; e += 4) {
        int s0 = csr[e], s1 = csr[e + 1], s2 = csr[e + 2], s3 = csr[e + 3];
        float w0 = sdis[e] * dn, w1 = sdis[e + 1] * dn;
        float w2 = sdis[e + 2] * dn, w3 = sdis[e + 3] * dn;
        u16x8 v0 = *(const u16x8*)&hw[(size_t)s0 * HID + c0];
        u16x8 v1 = *(const u16x8*)&hw[(size_t)s1 * HID + c0];
        u16x8 v2 = *(const u16x8*)&hw[(size_t)s2 * HID + c0];
        u16x8 v3 = *(const u16x8*)&hw[(size_t)s3 * HID + c0];
        float g[8];
        cvt8(v0, g);
#pragma unroll
        for (int j = 0; j < 8; ++j) acc[j] += g[j] * w0;
        cvt8(v1, g);
#pragma unroll
        for (int j = 0; j < 8; ++j) acc[j] += g[j] * w1;
        cvt8(v2, g);
#pragma unroll
        for (int j = 0; j < 8; ++j) acc[j] += g[j] * w2;
        cvt8(v3, g);
#pragma unroll
        for (int j = 0; j < 8; ++j) acc[j] += g[j] * w3;
    }
    for (; e < e1; ++e) {
        int s = csr[e];
        float w = sdis[e] * dn;
        u16x8 v = *(const u16x8*)&hw[(size_t)s * HID + c0];
        float g[8];
        cvt8(v, g);
#pragma unroll
        for (int j = 0; j < 8; ++j) acc[j] += g[j] * w;
    }

    float4 wo0 = *(const float4*)&Wo[c0];
    float4 wo1 = *(const float4*)&Wo[c0 + 4];
    float4 ww0 = *(const float4*)&Ww[c0];
    float4 ww1 = *(const float4*)&Ww[c0 + 4];
    float po = 0.f, pw = 0.f, h;
    h = fmaxf(acc[0], 0.f); po += h * wo0.x; pw += h * ww0.x;
    h = fmaxf(acc[1], 0.f); po += h * wo0.y; pw += h * ww0.y;
    h = fmaxf(acc[2], 0.f); po += h * wo0.z; pw += h * ww0.z;
    h = fmaxf(acc[3], 0.f); po += h * wo0.w; pw += h * ww0.w;
    h = fmaxf(acc[4], 0.f); po += h * wo1.x; pw += h * ww1.x;
    h = fmaxf(acc[5], 0.f); po += h * wo1.y; pw += h * ww1.y;
    h = fmaxf(acc[6], 0.f); po += h * wo1.z; pw += h * ww1.z;
    h = fmaxf(acc[7], 0.f); po += h * wo1.w; pw += h * ww1.w;

#pragma unroll
    for (int off = 32; off > 0; off >>= 1) {
        po += __shfl_down(po, off);
        pw += __shfl_down(pw, off);
    }
    if (lane == 0) {
        out[node]     = po + bo[0];
        out[N + node] = pw + bw[0];
    }
}

// ---------------------------------------------------------------------------
extern "C" void kernel_launch(void* const* d_in, const int* in_sizes, int n_in,
                              void* d_out, int out_size, void* d_ws, size_t ws_size,
                              hipStream_t stream) {
    const float* x  = (const float*)d_in[0];
    const int*   ei = (const int*)d_in[1];
    const float* W1 = (const float*)d_in[2];
    const float* b1 = (const float*)d_in[3];
    const float* W2 = (const float*)d_in[4];
    const float* b2 = (const float*)d_in[5];
    const float* Wo = (const float*)d_in[6];
    const float* bo = (const float*)d_in[7];
    const float* Ww = (const float*)d_in[8];
    const float* bw = (const float*)d_in[9];

    const int N = in_sizes[0] / DIN;           // 25000
    const int E = in_sizes[1] / 2;             // 200000
    const int Mpad = (N + 127) & ~127;         // 25088
    const int nb = (N + 255) / 256;            // 98

    char* ws = (char*)d_ws;
    size_t p = 0;
    auto alloc = [&](size_t bytes) -> char* {
        char* r = ws + p;
        p += (bytes + 255) & ~(size_t)255;
        return r;
    };
    int*   cnt    = (int*)alloc((size_t)N * 4);
    int*   offs   = (int*)alloc((size_t)(N + 1) * 4);
    int*   cursor = (int*)alloc((size_t)N * 4);
    int*   tmp    = (int*)alloc((size_t)N * 4);
    int*   bsum   = (int*)alloc(132 * 4);
    float* dis    = (float*)alloc((size_t)N * 4);
    int*   csr    = (int*)alloc((size_t)E * 4);
    float* sdis   = (float*)alloc((size_t)E * 4);
    unsigned short* xb  = (unsigned short*)alloc((size_t)Mpad * 512 * 2);
    unsigned short* Wt1 = (unsigned short*)alloc((size_t)512 * 512 * 2);
    unsigned short* Wt2 = (unsigned short*)alloc((size_t)512 * 512 * 2);
    unsigned short* hw  = (unsigned short*)alloc((size_t)Mpad * 512 * 2);
    unsigned short* h1  = (unsigned short*)alloc((size_t)Mpad * 512 * 2);

    const int* src = ei;
    const int* dst = ei + E;

    hipMemsetAsync(cnt, 0, (size_t)N * 4, stream);
    hipMemsetAsync(cursor, 0, (size_t)N * 4, stream);
    if (Mpad > N)
        hipMemsetAsync(h1 + (size_t)N * 512, 0, (size_t)(Mpad - N) * 512 * 2, stream);

    count_kernel<<<(E + 255) / 256, 256, 0, stream>>>(dst, cnt, E);
    scan1<<<nb, 256, 0, stream>>>(cnt, tmp, bsum, N);
    scan2<<<1, 128, 0, stream>>>(bsum, nb);
    scan3<<<nb, 256, 0, stream>>>(cnt, tmp, bsum, offs, dis, N, nb);
    fill_kernel<<<(E + 255) / 256, 256, 0, stream>>>(src, dst, offs, cursor, dis, csr, sdis, E);

    convert_pad<<<(Mpad * 64) / 256, 256, 0, stream>>>(x, xb, N);
    transpose_cvt<<<dim3(16, 16), dim3(32, 8), 0, stream>>>(W1, Wt1);
    transpose_cvt<<<dim3(16, 16), dim3(32, 8), 0, stream>>>(W2, Wt2);

    dim3 ggrid(Mpad / 128, 4);
    gemm_bf16<<<ggrid, 256, 0, stream>>>((const short*)xb, (const short*)Wt1, hw);
    agg_relu<<<(N + 3) / 4, 256, 0, stream>>>(hw, csr, sdis, offs, dis, b1, h1, N);
    gemm_bf16<<<ggrid, 256, 0, stream>>>((const short*)h1, (const short*)Wt2, hw);
    agg_relu_heads<<<(N + 3) / 4, 256, 0, stream>>>(hw, csr, sdis, offs, dis, b2,
                                                    Wo, bo, Ww, bw, (float*)d_out, N);
}